// Round 2
// baseline (1066.909 us; speedup 1.0000x reference)
//
#include <hip/hip_runtime.h>
#include <hip/hip_bf16.h>

// Problem constants (match reference)
#define BB   8
#define HH   8
#define NN   65536
#define DD   128
#define BDIM 64
#define KK   32

// All inputs/outputs are float32 per the reference dtypes.

// Workspace layout (float units)
#define OFF_SIMW 0u                       // B*H*N = 4194304
#define OFF_SIMR (OFF_SIMW + 4194304u)    // 4194304
#define OFF_NWK  (OFF_SIMR + 4194304u)    // 8192
#define OFF_NRK  (OFF_NWK + 8192u)        // 8192
#define OFF_CV   (OFF_NRK + 8192u)        // 8192
#define OFF_WIDX (OFF_CV + 8192u)         // 2048 (int)
#define OFF_WVAL (OFF_WIDX + 2048u)       // 2048
#define OFF_RIDX (OFF_WVAL + 2048u)       // 2048 (int)
#define OFF_RVAL (OFF_RIDX + 2048u)       // 2048
#define OFF_M2U  (OFF_RVAL + 2048u)       // B*256*D = 262144
#define OFF_RPH  (OFF_M2U + 262144u)      // 8192
// total = 8691712 floats = ~34.8 MB

// ---- helpers ----
__device__ __forceinline__ float brsum128(float v, float* sred, int tid) {
  // 128 threads = 2 waves; full-wave shuffle reduce then LDS combine
  #pragma unroll
  for (int o = 32; o > 0; o >>= 1) v += __shfl_xor(v, o);
  __syncthreads();
  if ((tid & 63) == 0) sred[tid >> 6] = v;
  __syncthreads();
  return sred[0] + sred[1];
}

// ---- K1: normalize keys (fold beta), MLP cvals, zero rph ----
__global__ __launch_bounds__(128) void k1_setup(
    const float* __restrict__ wkeys, const float* __restrict__ rkeys,
    const float* __restrict__ wvals,
    const float* __restrict__ beta_r, const float* __restrict__ beta_w,
    const float* __restrict__ W_b1, const float* __restrict__ b_b1,
    const float* __restrict__ W_b2, const float* __restrict__ b_b2,
    float* __restrict__ nwk, float* __restrict__ nrk,
    float* __restrict__ cvals, float* __restrict__ rph) {
  int g = blockIdx.x;      // b*H + h, 0..63
  int d = threadIdx.x;     // 0..127
  __shared__ float sred[2];
  __shared__ float wv_s[DD];
  __shared__ float hid[BDIM];

  rph[g * DD + d] = 0.f;   // 64*128 = 8192 total

  float wk = wkeys[g * DD + d];
  float rk = rkeys[g * DD + d];
  float wv = wvals[g * DD + d];
  wv_s[d] = wv;

  float s = brsum128(wk * wk, sred, d);
  nwk[g * DD + d] = wk / fmaxf(sqrtf(s), 1e-12f) * beta_w[g];
  s = brsum128(rk * rk, sred, d);
  nrk[g * DD + d] = rk / fmaxf(sqrtf(s), 1e-12f) * beta_r[g];

  __syncthreads();
  if (d < BDIM) {
    float a = b_b1[d];
    for (int dd = 0; dd < DD; ++dd) a += wv_s[dd] * W_b1[dd * BDIM + d];
    hid[d] = a * 0.5f * (1.f + erff(a * 0.70710678118654752f));  // exact gelu
  }
  __syncthreads();
  float c = b_b2[d];
  for (int j = 0; j < BDIM; ++j) c += hid[j] * W_b2[j * DD + d];
  cvals[g * DD + d] = c;
}

// ---- K2: big pass over memory: row norms + 16 dots -> simw, simr ----
// write sims use l2norm(memory); read sims use l2norm(memory + 1e-8)
// (exact match to reference's mem2 = l2norm(mem + 1e-8) for untouched rows;
//  the positive per-row decay scalar normalizes away)
__global__ __launch_bounds__(256) void k2_sims(
    const float* __restrict__ mem,
    const float* __restrict__ nwk, const float* __restrict__ nrk,
    float* __restrict__ simw, float* __restrict__ simr) {
  int blk = blockIdx.x;          // 0..2047
  int b   = blk >> 8;
  int n   = ((blk & 255) << 8) + threadIdx.x;   // row in [0,N)
  const float4* rowp = (const float4*)(mem + ((size_t)b * NN + n) * DD);

  float dw[HH] = {0,0,0,0,0,0,0,0};
  float dr[HH] = {0,0,0,0,0,0,0,0};
  float nw = 0.f, nr = 0.f;
  const float* kw = nwk + b * HH * DD;   // block-uniform -> scalar loads
  const float* kr = nrk + b * HH * DD;

  for (int c = 0; c < 32; ++c) {
    float4 q = rowp[c];
    float x[4] = {q.x, q.y, q.z, q.w};
    #pragma unroll
    for (int e = 0; e < 4; ++e) {
      float xv = x[e];
      float xr = xv + 1e-8f;
      nw += xv * xv;
      nr += xr * xr;
      int d = c * 4 + e;
      #pragma unroll
      for (int h = 0; h < HH; ++h) {
        dw[h] += xv * kw[h * DD + d];
        dr[h] += xr * kr[h * DD + d];
      }
    }
  }
  float riw = 1.f / fmaxf(sqrtf(nw), 1e-12f);
  float rir = 1.f / fmaxf(sqrtf(nr), 1e-12f);
  #pragma unroll
  for (int h = 0; h < HH; ++h) {
    simw[(size_t)(b * HH + h) * NN + n] = dw[h] * riw;
    simr[(size_t)(b * HH + h) * NN + n] = dr[h] * rir;
  }
}

// ---- K3/K5: exact top-32 + softmax via adaptive histogram select ----
#define NBKT 1024
#define MAXC 4096
__global__ __launch_bounds__(256) void k_topk(
    const float* __restrict__ sims, int* __restrict__ oidx, float* __restrict__ oval) {
  int blk = blockIdx.x;          // (b*H+h), 0..63
  int tid = threadIdx.x;
  const float* s = sims + (size_t)blk * NN;
  __shared__ float redv[256];
  __shared__ int   redp[256];
  __shared__ unsigned hist[NBKT];
  __shared__ float cv[MAXC];
  __shared__ int   ci[MAXC];
  __shared__ float sM, sm, sscale;
  __shared__ int   sthr, scnt;
  __shared__ float selv[KK];
  __shared__ int   seli[KK];

  // pass A: block min/max
  float mx = -1e30f, mn = 1e30f;
  for (int i = tid; i < NN; i += 256) { float v = s[i]; mx = fmaxf(mx, v); mn = fminf(mn, v); }
  redv[tid] = mx; __syncthreads();
  for (int st = 128; st > 0; st >>= 1) { if (tid < st) redv[tid] = fmaxf(redv[tid], redv[tid + st]); __syncthreads(); }
  if (tid == 0) sM = redv[0];
  __syncthreads();
  redv[tid] = mn; __syncthreads();
  for (int st = 128; st > 0; st >>= 1) { if (tid < st) redv[tid] = fminf(redv[tid], redv[tid + st]); __syncthreads(); }
  if (tid == 0) {
    sm = redv[0];
    float r = sM - sm;
    sscale = (r > 0.f) ? ((float)NBKT / r) : 0.f;
    scnt = 0;
  }
  for (int i = tid; i < NBKT; i += 256) hist[i] = 0u;
  __syncthreads();

  // pass B: histogram
  float m_ = sm, sc_ = sscale;
  for (int i = tid; i < NN; i += 256) {
    int bkt = (int)((s[i] - m_) * sc_);
    bkt = min(NBKT - 1, max(0, bkt));
    atomicAdd(&hist[bkt], 1u);
  }
  __syncthreads();
  if (tid == 0) {
    unsigned acc = 0; int t = NBKT - 1;
    for (; t >= 0; --t) { acc += hist[t]; if (acc >= KK) break; }
    sthr = (t < 0) ? 0 : t;
  }
  __syncthreads();

  // pass C: compact candidates (bucket >= threshold bucket -> superset of top-32)
  int thr = sthr;
  for (int i = tid; i < NN; i += 256) {
    float v = s[i];
    int bkt = (int)((v - m_) * sc_);
    bkt = min(NBKT - 1, max(0, bkt));
    if (bkt >= thr) {
      int p = atomicAdd(&scnt, 1);
      if (p < MAXC) { cv[p] = v; ci[p] = i; }
    }
  }
  __syncthreads();
  int nc = min(scnt, MAXC);

  // 32 exact extractions (ties -> lower index, matching lax.top_k)
  for (int k = 0; k < KK; ++k) {
    float bv = -1e30f; int bp = -1;
    for (int j = tid; j < nc; j += 256) {
      float v = cv[j];
      if (v > bv || (v == bv && bp >= 0 && v > -1e30f && ci[j] < ci[bp])) { bv = v; bp = j; }
    }
    redv[tid] = bv; redp[tid] = bp; __syncthreads();
    for (int st = 128; st > 0; st >>= 1) {
      if (tid < st) {
        float v1 = redv[tid], v2 = redv[tid + st];
        int   p1 = redp[tid], p2 = redp[tid + st];
        bool take = (p1 < 0) || (p2 >= 0 && (v2 > v1 || (v2 == v1 && ci[p2] < ci[p1])));
        if (take) { redv[tid] = v2; redp[tid] = p2; }
      }
      __syncthreads();
    }
    if (tid == 0) {
      int wp = redp[0];
      selv[k] = redv[0]; seli[k] = ci[wp];
      cv[wp] = -1e30f;
    }
    __syncthreads();
  }

  if (tid == 0) {
    float m0 = selv[0], ssum = 0.f, es[KK];
    for (int k = 0; k < KK; ++k) { es[k] = expf(selv[k] - m0); ssum += es[k]; }
    float inv = 1.f / ssum;
    for (int k = 0; k < KK; ++k) {
      oidx[blk * KK + k] = seli[k];
      oval[blk * KK + k] = es[k] * inv;
    }
  }
}

// ---- K4: apply erase/add to touched rows, store unit rows, patch simr ----
__global__ __launch_bounds__(128) void k4_write(
    const float* __restrict__ mem, const float* __restrict__ erase,
    const float* __restrict__ adg,
    const int* __restrict__ widx, const float* __restrict__ wval,
    const float* __restrict__ cvals, const float* __restrict__ nrk,
    float* __restrict__ mem2u, float* __restrict__ simr) {
  int b  = blockIdx.x >> 8;
  int sl = blockIdx.x & 255;          // slot in b's write list (h*32+k)
  const int* wi = widx + b * HH * KK;
  int n = wi[sl];
  for (int j = 0; j < sl; ++j) if (wi[j] == n) return;  // not first occurrence

  int d = threadIdx.x;
  __shared__ float sred[2];
  float E = 0.f, addd = 0.f;
  #pragma unroll
  for (int h = 0; h < HH; ++h) {
    float er = erase[b * HH + h];
    float ag = adg[b * HH + h];
    float aw = 0.f;
    for (int k = 0; k < KK; ++k) {
      int j = h * KK + k;
      if (wi[j] == n) { float wv = wval[b * HH * KK + j]; E += wv * er; aw += wv; }
    }
    addd += aw * ag * cvals[(b * HH + h) * DD + d];
  }
  float mval = mem[((size_t)b * NN + n) * DD + d];
  float v = mval * (1.f - E * 0.125f) + addd * 0.125f + 1e-8f;
  float S = brsum128(v * v, sred, d);
  float u = v / fmaxf(sqrtf(S), 1e-12f);
  mem2u[(size_t)(b * 256 + sl) * DD + d] = u;
  #pragma unroll
  for (int h = 0; h < HH; ++h) {
    float p = brsum128(nrk[(b * HH + h) * DD + d] * u, sred, d);
    if (d == 0) simr[(size_t)(b * HH + h) * NN + n] = p;
  }
}

// ---- K6: gather read rows -> rph (atomic accumulate) ----
__global__ __launch_bounds__(128) void k6_gather(
    const float* __restrict__ mem, const float* __restrict__ decay,
    const int* __restrict__ widx, const int* __restrict__ ridx,
    const float* __restrict__ rval, const float* __restrict__ mem2u,
    float* __restrict__ rph) {
  int b   = blockIdx.x >> 8;
  int rem = blockIdx.x & 255;    // h*32+k
  int d   = threadIdx.x;
  __shared__ float sred[2];
  int n   = ridx[b * HH * KK + rem];
  float w = rval[b * HH * KK + rem];
  float sc = 1.f / (1.f + expf(-decay[n]));
  const int* wi = widx + b * HH * KK;
  int slot = -1;
  for (int j = 0; j < 256; ++j) if (wi[j] == n) { slot = j; break; }
  float u;
  if (slot >= 0) {
    u = mem2u[(size_t)(b * 256 + slot) * DD + d];
  } else {
    float v = mem[((size_t)b * NN + n) * DD + d] + 1e-8f;
    float S = brsum128(v * v, sred, d);
    u = v / fmaxf(sqrtf(S), 1e-12f);
  }
  int h = rem >> 5;
  atomicAdd(&rph[(b * HH + h) * DD + d], w * sc * u);
}

// ---- K7: merge matvec + LayerNorm -> out ----
__global__ __launch_bounds__(128) void k7_merge(
    const float* __restrict__ rph, const float* __restrict__ W_merge,
    const float* __restrict__ b_merge, const float* __restrict__ ln_g,
    const float* __restrict__ ln_b, float* __restrict__ out) {
  int b = blockIdx.x;
  int d = threadIdx.x;
  __shared__ float sred[2];
  float acc = b_merge[d];
  for (int j = 0; j < HH * DD; ++j)
    acc += rph[b * HH * DD + j] * W_merge[j * DD + d];
  float mu  = brsum128(acc, sred, d) * (1.f / DD);
  float dv  = acc - mu;
  float var = brsum128(dv * dv, sred, d) * (1.f / DD);
  float o = dv * rsqrtf(var + 1e-5f) * ln_g[d] + ln_b[d];
  out[b * DD + d] = o;
}

extern "C" void kernel_launch(void* const* d_in, const int* in_sizes, int n_in,
                              void* d_out, int out_size, void* d_ws, size_t ws_size,
                              hipStream_t stream) {
  const float* memory  = (const float*)d_in[0];
  const float* rkeys   = (const float*)d_in[1];
  const float* wkeys   = (const float*)d_in[2];
  const float* wvals   = (const float*)d_in[3];
  const float* erase   = (const float*)d_in[4];
  const float* adg     = (const float*)d_in[5];
  const float* beta_r  = (const float*)d_in[6];
  const float* beta_w  = (const float*)d_in[7];
  const float* W_b1    = (const float*)d_in[8];
  const float* b_b1    = (const float*)d_in[9];
  const float* W_b2    = (const float*)d_in[10];
  const float* b_b2    = (const float*)d_in[11];
  const float* W_merge = (const float*)d_in[12];
  const float* b_merge = (const float*)d_in[13];
  const float* ln_g    = (const float*)d_in[14];
  const float* ln_b    = (const float*)d_in[15];
  const float* decay   = (const float*)d_in[16];

  float* ws   = (float*)d_ws;        // needs ~35 MB
  float* simw = ws + OFF_SIMW;
  float* simr = ws + OFF_SIMR;
  float* nwk  = ws + OFF_NWK;
  float* nrk  = ws + OFF_NRK;
  float* cv   = ws + OFF_CV;
  int*   widx = (int*)(ws + OFF_WIDX);
  float* wval = ws + OFF_WVAL;
  int*   ridx = (int*)(ws + OFF_RIDX);
  float* rval = ws + OFF_RVAL;
  float* m2u  = ws + OFF_M2U;
  float* rph  = ws + OFF_RPH;

  hipLaunchKernelGGL(k1_setup, dim3(BB * HH), dim3(128), 0, stream,
                     wkeys, rkeys, wvals, beta_r, beta_w, W_b1, b_b1, W_b2, b_b2,
                     nwk, nrk, cv, rph);
  hipLaunchKernelGGL(k2_sims, dim3(BB * (NN / 256)), dim3(256), 0, stream,
                     memory, nwk, nrk, simw, simr);
  hipLaunchKernelGGL(k_topk, dim3(BB * HH), dim3(256), 0, stream, simw, widx, wval);
  hipLaunchKernelGGL(k4_write, dim3(BB * 256), dim3(128), 0, stream,
                     memory, erase, adg, widx, wval, cv, nrk, m2u, simr);
  hipLaunchKernelGGL(k_topk, dim3(BB * HH), dim3(256), 0, stream, simr, ridx, rval);
  hipLaunchKernelGGL(k6_gather, dim3(BB * 256), dim3(128), 0, stream,
                     memory, decay, widx, ridx, rval, m2u, rph);
  hipLaunchKernelGGL(k7_merge, dim3(BB), dim3(128), 0, stream,
                     rph, W_merge, b_merge, ln_g, ln_b, (float*)d_out);
}

// Round 3
// 628.644 us; speedup vs baseline: 1.6972x; 1.6972x over previous
//
#include <hip/hip_runtime.h>
#include <hip/hip_bf16.h>

// Problem constants (match reference)
#define BB   8
#define HH   8
#define NN   65536
#define DD   128
#define BDIM 64
#define KK   32

// All inputs/outputs are float32 per the reference dtypes.

// Workspace layout (float units)
#define OFF_SIMW 0u                       // B*H*N = 4194304
#define OFF_SIMR (OFF_SIMW + 4194304u)    // 4194304
#define OFF_NWK  (OFF_SIMR + 4194304u)    // 8192
#define OFF_NRK  (OFF_NWK + 8192u)        // 8192
#define OFF_CV   (OFF_NRK + 8192u)        // 8192
#define OFF_WIDX (OFF_CV + 8192u)         // 2048 (int)
#define OFF_WVAL (OFF_WIDX + 2048u)       // 2048
#define OFF_RIDX (OFF_WVAL + 2048u)       // 2048 (int)
#define OFF_RVAL (OFF_RIDX + 2048u)       // 2048
#define OFF_M2U  (OFF_RVAL + 2048u)       // B*256*D = 262144
#define OFF_RPH  (OFF_M2U + 262144u)      // 8192
// total = 8691712 floats = ~34.8 MB

// ---- helpers ----
__device__ __forceinline__ float brsum128(float v, float* sred, int tid) {
  #pragma unroll
  for (int o = 32; o > 0; o >>= 1) v += __shfl_xor(v, o);
  __syncthreads();
  if ((tid & 63) == 0) sred[tid >> 6] = v;
  __syncthreads();
  return sred[0] + sred[1];
}

// ---- K1: normalize keys (fold beta), MLP cvals, zero rph ----
__global__ __launch_bounds__(128) void k1_setup(
    const float* __restrict__ wkeys, const float* __restrict__ rkeys,
    const float* __restrict__ wvals,
    const float* __restrict__ beta_r, const float* __restrict__ beta_w,
    const float* __restrict__ W_b1, const float* __restrict__ b_b1,
    const float* __restrict__ W_b2, const float* __restrict__ b_b2,
    float* __restrict__ nwk, float* __restrict__ nrk,
    float* __restrict__ cvals, float* __restrict__ rph) {
  int g = blockIdx.x;      // b*H + h, 0..63
  int d = threadIdx.x;     // 0..127
  __shared__ float sred[2];
  __shared__ float wv_s[DD];
  __shared__ float hid[BDIM];

  rph[g * DD + d] = 0.f;

  float wk = wkeys[g * DD + d];
  float rk = rkeys[g * DD + d];
  float wv = wvals[g * DD + d];
  wv_s[d] = wv;

  float s = brsum128(wk * wk, sred, d);
  nwk[g * DD + d] = wk / fmaxf(sqrtf(s), 1e-12f) * beta_w[g];
  s = brsum128(rk * rk, sred, d);
  nrk[g * DD + d] = rk / fmaxf(sqrtf(s), 1e-12f) * beta_r[g];

  __syncthreads();
  if (d < BDIM) {
    float a = b_b1[d];
    #pragma unroll 4
    for (int dd = 0; dd < DD; ++dd) a += wv_s[dd] * W_b1[dd * BDIM + d];
    hid[d] = a * 0.5f * (1.f + erff(a * 0.70710678118654752f));  // exact gelu
  }
  __syncthreads();
  float c = b_b2[d];
  #pragma unroll 4
  for (int j = 0; j < BDIM; ++j) c += hid[j] * W_b2[j * DD + d];
  cvals[g * DD + d] = c;
}

// ---- K2: big pass over memory: row norms + 16 dots -> simw, simr ----
// Per-lane row streaming, but consume 128B line-groups with 8 back-to-back
// float4 loads so every fetched line is fully used while in flight.
__global__ __launch_bounds__(256) void k2_sims(
    const float* __restrict__ mem,
    const float* __restrict__ nwk, const float* __restrict__ nrk,
    float* __restrict__ simw, float* __restrict__ simr) {
  int blk = blockIdx.x;          // 0..2047
  int b   = blk >> 8;
  int n   = ((blk & 255) << 8) + threadIdx.x;   // row in [0,N)
  const float4* rowp = (const float4*)(mem + ((size_t)b * NN + n) * DD);

  float dw[HH] = {0,0,0,0,0,0,0,0};
  float dr[HH] = {0,0,0,0,0,0,0,0};
  float nw = 0.f, nr = 0.f;
  const float* kw = nwk + b * HH * DD;   // block-uniform -> scalar loads
  const float* kr = nrk + b * HH * DD;

  for (int g = 0; g < 4; ++g) {          // 4 groups x 128B
    float4 q[8];
    #pragma unroll
    for (int i = 0; i < 8; ++i) q[i] = rowp[g * 8 + i];
    #pragma unroll
    for (int i = 0; i < 8; ++i) {
      float xs[4] = {q[i].x, q[i].y, q[i].z, q[i].w};
      #pragma unroll
      for (int e = 0; e < 4; ++e) {
        float xv = xs[e];
        float xr = xv + 1e-8f;
        nw += xv * xv;
        nr += xr * xr;
        int d = g * 32 + i * 4 + e;
        #pragma unroll
        for (int h = 0; h < HH; ++h) {
          dw[h] += xv * kw[h * DD + d];
          dr[h] += xr * kr[h * DD + d];
        }
      }
    }
  }
  float riw = 1.f / fmaxf(sqrtf(nw), 1e-12f);
  float rir = 1.f / fmaxf(sqrtf(nr), 1e-12f);
  #pragma unroll
  for (int h = 0; h < HH; ++h) {
    simw[(size_t)(b * HH + h) * NN + n] = dw[h] * riw;
    simr[(size_t)(b * HH + h) * NN + n] = dr[h] * rir;
  }
}

// ---- K3/K5: exact top-32 + softmax via adaptive histogram select ----
#define NBKT 1024
#define MAXC 4096
__global__ __launch_bounds__(256) void k_topk(
    const float* __restrict__ sims, int* __restrict__ oidx, float* __restrict__ oval) {
  int blk = blockIdx.x;          // (b*H+h), 0..63
  int tid = threadIdx.x;
  const float*  s  = sims + (size_t)blk * NN;
  const float4* s4 = (const float4*)s;
  __shared__ float redv[256];
  __shared__ unsigned hist[NBKT];
  __shared__ float cv[MAXC];
  __shared__ int   ci[MAXC];
  __shared__ float sM, sm, sscale;
  __shared__ int   sthr, scnt;
  __shared__ float selv[KK];
  __shared__ int   seli[KK];

  // pass A: block min/max (float4, unrolled)
  float mx = -1e30f, mn = 1e30f;
  #pragma unroll 4
  for (int i = tid; i < NN / 4; i += 256) {
    float4 v = s4[i];
    mx = fmaxf(mx, fmaxf(fmaxf(v.x, v.y), fmaxf(v.z, v.w)));
    mn = fminf(mn, fminf(fminf(v.x, v.y), fminf(v.z, v.w)));
  }
  redv[tid] = mx; __syncthreads();
  for (int st = 128; st > 0; st >>= 1) { if (tid < st) redv[tid] = fmaxf(redv[tid], redv[tid + st]); __syncthreads(); }
  if (tid == 0) sM = redv[0];
  __syncthreads();
  redv[tid] = mn; __syncthreads();
  for (int st = 128; st > 0; st >>= 1) { if (tid < st) redv[tid] = fminf(redv[tid], redv[tid + st]); __syncthreads(); }
  if (tid == 0) {
    sm = redv[0];
    float r = sM - sm;
    sscale = (r > 0.f) ? ((float)NBKT / r) : 0.f;
    scnt = 0;
  }
  for (int i = tid; i < NBKT; i += 256) hist[i] = 0u;
  __syncthreads();

  // pass B: histogram
  float m_ = sm, sc_ = sscale;
  #pragma unroll 2
  for (int i = tid; i < NN / 4; i += 256) {
    float4 v = s4[i];
    float xs[4] = {v.x, v.y, v.z, v.w};
    #pragma unroll
    for (int e = 0; e < 4; ++e) {
      int bkt = (int)((xs[e] - m_) * sc_);
      bkt = min(NBKT - 1, max(0, bkt));
      atomicAdd(&hist[bkt], 1u);
    }
  }
  __syncthreads();
  if (tid == 0) {
    unsigned acc = 0; int t = NBKT - 1;
    for (; t >= 0; --t) { acc += hist[t]; if (acc >= KK) break; }
    sthr = (t < 0) ? 0 : t;
  }
  __syncthreads();

  // pass C: compact candidates (bucket >= threshold -> superset of top-32)
  int thr = sthr;
  #pragma unroll 2
  for (int i = tid; i < NN / 4; i += 256) {
    float4 v = s4[i];
    float xs[4] = {v.x, v.y, v.z, v.w};
    #pragma unroll
    for (int e = 0; e < 4; ++e) {
      float vv = xs[e];
      int bkt = (int)((vv - m_) * sc_);
      bkt = min(NBKT - 1, max(0, bkt));
      if (bkt >= thr) {
        int p = atomicAdd(&scnt, 1);
        if (p < MAXC) { cv[p] = vv; ci[p] = i * 4 + e; }
      }
    }
  }
  __syncthreads();
  int nc = min(scnt, MAXC);

  // 32 exact extractions by wave 0 only: 64-bit key = (ordered(v) << 32) | ~idx
  // (value desc, index asc — matches lax.top_k), shuffle-reduced, no barriers.
  if (tid < 64) {
    for (int k = 0; k < KK; ++k) {
      unsigned long long best = 0ull, lbest = 0ull;
      int lj = -1;
      for (int j = tid; j < nc; j += 64) {
        float v = cv[j];
        unsigned u = __float_as_uint(v);
        u = (u & 0x80000000u) ? ~u : (u | 0x80000000u);
        unsigned long long key = ((unsigned long long)u << 32) | (unsigned)(~(unsigned)ci[j]);
        if (key > lbest) { lbest = key; lj = j; }
      }
      best = lbest;
      #pragma unroll
      for (int o = 32; o > 0; o >>= 1) {
        unsigned long long t = __shfl_xor(best, o);
        if (t > best) best = t;
      }
      if (lbest == best && lj >= 0) cv[lj] = -1e30f;   // owner removes winner
      if (tid == 0) {
        unsigned u = (unsigned)(best >> 32);
        float v = (u & 0x80000000u) ? __uint_as_float(u & 0x7fffffffu) : __uint_as_float(~u);
        selv[k] = v;
        seli[k] = (int)~(unsigned)(best & 0xffffffffu);
      }
    }
    if (tid == 0) {
      float m0 = selv[0], ssum = 0.f;   // selv descending -> selv[0] is max
      float es[KK];
      #pragma unroll
      for (int k = 0; k < KK; ++k) { es[k] = expf(selv[k] - m0); ssum += es[k]; }
      float inv = 1.f / ssum;
      #pragma unroll
      for (int k = 0; k < KK; ++k) {
        oidx[blk * KK + k] = seli[k];
        oval[blk * KK + k] = es[k] * inv;
      }
    }
  }
}

// ---- K4: apply erase/add to touched rows, store unit rows, patch simr ----
__global__ __launch_bounds__(128) void k4_write(
    const float* __restrict__ mem, const float* __restrict__ erase,
    const float* __restrict__ adg,
    const int* __restrict__ widx, const float* __restrict__ wval,
    const float* __restrict__ cvals, const float* __restrict__ nrk,
    float* __restrict__ mem2u, float* __restrict__ simr) {
  int b  = blockIdx.x >> 8;
  int sl = blockIdx.x & 255;          // slot in b's write list (h*32+k)
  int d  = threadIdx.x;
  __shared__ int   swi[256];
  __shared__ float swv[256];
  __shared__ float sred[2 * 9];

  swi[d]       = widx[b * 256 + d];
  swi[d + 128] = widx[b * 256 + d + 128];
  swv[d]       = wval[b * 256 + d];
  swv[d + 128] = wval[b * 256 + d + 128];
  __syncthreads();

  int n = swi[sl];
  for (int j = 0; j < sl; ++j) if (swi[j] == n) return;  // uniform: whole block

  float E = 0.f, addd = 0.f;
  #pragma unroll
  for (int h = 0; h < HH; ++h) {
    float er = erase[b * HH + h];
    float ag = adg[b * HH + h];
    float aw = 0.f;
    #pragma unroll 4
    for (int k = 0; k < KK; ++k) {
      int j = h * KK + k;
      if (swi[j] == n) { float wv = swv[j]; E += wv * er; aw += wv; }
    }
    addd += aw * ag * cvals[(b * HH + h) * DD + d];
  }
  float mval = mem[((size_t)b * NN + n) * DD + d];
  float v = mval * (1.f - E * 0.125f) + addd * 0.125f + 1e-8f;

  // one fused 9-value reduction: [0]=v^2, [1..8]=nrk_h[d]*v
  float r[9];
  r[0] = v * v;
  #pragma unroll
  for (int h = 0; h < HH; ++h) r[1 + h] = nrk[(b * HH + h) * DD + d] * v;
  #pragma unroll
  for (int o = 32; o > 0; o >>= 1) {
    #pragma unroll
    for (int i = 0; i < 9; ++i) r[i] += __shfl_xor(r[i], o);
  }
  if ((d & 63) == 0) {
    int w = d >> 6;
    #pragma unroll
    for (int i = 0; i < 9; ++i) sred[w * 9 + i] = r[i];
  }
  __syncthreads();
  float S    = sred[0] + sred[9];
  float rinv = 1.f / fmaxf(sqrtf(S), 1e-12f);
  mem2u[(size_t)(b * 256 + sl) * DD + d] = v * rinv;
  if (d < HH) simr[(size_t)(b * HH + d) * NN + n] = (sred[1 + d] + sred[9 + 1 + d]) * rinv;
}

// ---- K6: gather read rows -> rph (atomic accumulate) ----
__global__ __launch_bounds__(128) void k6_gather(
    const float* __restrict__ mem, const float* __restrict__ decay,
    const int* __restrict__ widx, const int* __restrict__ ridx,
    const float* __restrict__ rval, const float* __restrict__ mem2u,
    float* __restrict__ rph) {
  int b   = blockIdx.x >> 8;
  int rem = blockIdx.x & 255;    // h*32+k
  int d   = threadIdx.x;
  __shared__ int swi[256];
  __shared__ float sred[2];
  swi[d]       = widx[b * 256 + d];
  swi[d + 128] = widx[b * 256 + d + 128];
  __syncthreads();

  int n   = ridx[b * HH * KK + rem];
  float w = rval[b * HH * KK + rem];
  float sc = 1.f / (1.f + expf(-decay[n]));
  int slot = -1;
  for (int j = 0; j < 256; ++j) if (swi[j] == n) { slot = j; break; }  // uniform
  float u;
  if (slot >= 0) {
    u = mem2u[(size_t)(b * 256 + slot) * DD + d];
  } else {
    float v = mem[((size_t)b * NN + n) * DD + d] + 1e-8f;
    float S = brsum128(v * v, sred, d);
    u = v / fmaxf(sqrtf(S), 1e-12f);
  }
  int h = rem >> 5;
  atomicAdd(&rph[(b * HH + h) * DD + d], w * sc * u);
}

// ---- K7: merge matvec + LayerNorm -> out (512 threads, split-K) ----
__global__ __launch_bounds__(512) void k7_merge(
    const float* __restrict__ rph, const float* __restrict__ W_merge,
    const float* __restrict__ b_merge, const float* __restrict__ ln_g,
    const float* __restrict__ ln_b, float* __restrict__ out) {
  int b = blockIdx.x;
  int tid = threadIdx.x;
  int d = tid & 127;
  int p = tid >> 7;              // 0..3
  __shared__ float acc_s[4][DD];
  __shared__ float accf[DD];
  __shared__ float smu, svar;

  float a = 0.f;
  int j0 = p * 256;
  #pragma unroll 4
  for (int j = j0; j < j0 + 256; ++j)
    a += rph[b * HH * DD + j] * W_merge[j * DD + d];
  acc_s[p][d] = a;
  __syncthreads();
  if (tid < DD) accf[d] = b_merge[d] + acc_s[0][d] + acc_s[1][d] + acc_s[2][d] + acc_s[3][d];
  __syncthreads();
  if (tid < 64) {
    float x0 = accf[tid], x1 = accf[tid + 64];
    float s1 = x0 + x1, s2 = x0 * x0 + x1 * x1;
    #pragma unroll
    for (int o = 32; o > 0; o >>= 1) { s1 += __shfl_xor(s1, o); s2 += __shfl_xor(s2, o); }
    if (tid == 0) { smu = s1 * (1.f / DD); svar = s2 * (1.f / DD) - smu * smu; }
  }
  __syncthreads();
  if (tid < DD)
    out[b * DD + d] = (accf[d] - smu) * rsqrtf(svar + 1e-5f) * ln_g[d] + ln_b[d];
}

extern "C" void kernel_launch(void* const* d_in, const int* in_sizes, int n_in,
                              void* d_out, int out_size, void* d_ws, size_t ws_size,
                              hipStream_t stream) {
  const float* memory  = (const float*)d_in[0];
  const float* rkeys   = (const float*)d_in[1];
  const float* wkeys   = (const float*)d_in[2];
  const float* wvals   = (const float*)d_in[3];
  const float* erase   = (const float*)d_in[4];
  const float* adg     = (const float*)d_in[5];
  const float* beta_r  = (const float*)d_in[6];
  const float* beta_w  = (const float*)d_in[7];
  const float* W_b1    = (const float*)d_in[8];
  const float* b_b1    = (const float*)d_in[9];
  const float* W_b2    = (const float*)d_in[10];
  const float* b_b2    = (const float*)d_in[11];
  const float* W_merge = (const float*)d_in[12];
  const float* b_merge = (const float*)d_in[13];
  const float* ln_g    = (const float*)d_in[14];
  const float* ln_b    = (const float*)d_in[15];
  const float* decay   = (const float*)d_in[16];

  float* ws   = (float*)d_ws;        // needs ~35 MB
  float* simw = ws + OFF_SIMW;
  float* simr = ws + OFF_SIMR;
  float* nwk  = ws + OFF_NWK;
  float* nrk  = ws + OFF_NRK;
  float* cv   = ws + OFF_CV;
  int*   widx = (int*)(ws + OFF_WIDX);
  float* wval = ws + OFF_WVAL;
  int*   ridx = (int*)(ws + OFF_RIDX);
  float* rval = ws + OFF_RVAL;
  float* m2u  = ws + OFF_M2U;
  float* rph  = ws + OFF_RPH;

  hipLaunchKernelGGL(k1_setup, dim3(BB * HH), dim3(128), 0, stream,
                     wkeys, rkeys, wvals, beta_r, beta_w, W_b1, b_b1, W_b2, b_b2,
                     nwk, nrk, cv, rph);
  hipLaunchKernelGGL(k2_sims, dim3(BB * (NN / 256)), dim3(256), 0, stream,
                     memory, nwk, nrk, simw, simr);
  hipLaunchKernelGGL(k_topk, dim3(BB * HH), dim3(256), 0, stream, simw, widx, wval);
  hipLaunchKernelGGL(k4_write, dim3(BB * 256), dim3(128), 0, stream,
                     memory, erase, adg, widx, wval, cv, nrk, m2u, simr);
  hipLaunchKernelGGL(k_topk, dim3(BB * HH), dim3(256), 0, stream, simr, ridx, rval);
  hipLaunchKernelGGL(k6_gather, dim3(BB * 256), dim3(128), 0, stream,
                     memory, decay, widx, ridx, rval, m2u, rph);
  hipLaunchKernelGGL(k7_merge, dim3(BB), dim3(512), 0, stream,
                     rph, W_merge, b_merge, ln_g, ln_b, (float*)d_out);
}